// Round 13
// baseline (341.147 us; speedup 1.0000x reference)
//
#include <hip/hip_runtime.h>

// ---------------- problem constants ----------------
#define NN 100000      // nodes
#define NE 1600000     // edges (without self loops)
#define DD 128         // feature dim
#define EPSV 1e-5f

#define NSTRIP 6250            // NN/16 row-strips for MFMA gemms

// bucket sort: 196 buckets of 512 nodes; 782 histplace blocks of 2048 edges
#define BSHIFT 9
#define NBUCK 196
#define EPB 2048
#define NHB 782
#define CAP 12288              // fixed bucket capacity (mean 8163: 45 sigma headroom)

#define NSHARD 32              // stats atomic shards
#define STATS_F (4 * NSHARD * 128)   // 2 stages x (sum|sq)[32][128]

typedef __attribute__((ext_vector_type(8))) __bf16 bf16x8;
typedef __attribute__((ext_vector_type(4))) float f32x4;

union BF8 {                // bit-level construction of MFMA bf16 fragments
    ushort  us[8];
    uint    ui[4];
    uint4   u4;
    bf16x8  v;
};

__device__ __forceinline__ ushort f2bf(float f) {   // RNE fp32 -> bf16 bits
    uint u = __float_as_uint(f);
    return (ushort)((u + 0x7fffu + ((u >> 16) & 1u)) >> 16);
}
__device__ __forceinline__ float bflo(uint u) { return __uint_as_float(u << 16); }
__device__ __forceinline__ float bfhi(uint u) { return __uint_as_float(u & 0xffff0000u); }

// ------ weight prep (runs FIRST): 3x W[128x128] fp32 -> B-frag bf16 + zero scratch ------
__global__ void k_prepw3(const float* __restrict__ WA, const float* __restrict__ WB,
                         const float* __restrict__ WC, ushort* __restrict__ Wf,
                         int* __restrict__ cnt, float* __restrict__ statsG) {
    int gid = blockIdx.x * 256 + threadIdx.x;        // 0..6143
    if (gid < 256) cnt[gid] = 0;
    for (int i = gid; i < STATS_F; i += 24 * 256) statsG[i] = 0.f;

    int which = blockIdx.x >> 3;
    const float* W = (which == 0) ? WA : ((which == 1) ? WB : WC);
    int t = (blockIdx.x & 7) * 256 + threadIdx.x;    // 0..2047
    int lane = t & 63;
    int kt = (t >> 6) & 3;
    int nt = t >> 8;
    int quad = lane >> 4;
    int n = nt * 16 + (lane & 15);
    BF8 f;
    #pragma unroll
    for (int j = 0; j < 8; j++)
        f.us[j] = f2bf(W[(kt * 32 + quad * 8 + j) * DD + n]);
    ((uint4*)(Wf + (size_t)which * 2048 * 8))[t] = f.u4;
}

// ---- FUSED hist+place+GEMM1: blocks<NHB do bucket hist + fixed-capacity place;
//      ALL 1563 blocks run gemmA (Y = bf16(X@W0), UNSCALED — dinv applied in agg,
//      so the gemm no longer depends on the graph build at all). ----
__global__ __launch_bounds__(256)
void kb_histplaceA(const int* __restrict__ row, const int* __restrict__ col,
                   int* __restrict__ cnt, uint* __restrict__ ebuf,
                   const float* __restrict__ X, const ushort* __restrict__ Wf,
                   ushort* __restrict__ Y) {
    const int t = threadIdx.x;
    const int bid = blockIdx.x;

    if (bid < NHB) {                       // block-uniform branch: hist+place pass
        __shared__ int h[256];
        __shared__ int curl[256];          // per-bucket cursor (offset within bucket)
        h[t] = 0;
        __syncthreads();
        int e0 = bid * EPB;
        #pragma unroll
        for (int j = 0; j < 8; j++) {
            int e = e0 + t + j * 256;
            if (e < NE) atomicAdd(&h[col[e] >> BSHIFT], 1);
        }
        __syncthreads();
        int c = h[t];
        curl[t] = c ? atomicAdd(&cnt[t], c) : 0;   // block's reservation in bucket t
        __syncthreads();
        #pragma unroll
        for (int j = 0; j < 8; j++) {
            int e = e0 + t + j * 256;
            if (e < NE) {
                int cc = col[e];
                int b = cc >> BSHIFT;
                int pl = atomicAdd(&curl[b], 1);
                if (pl < CAP)
                    ebuf[(size_t)b * CAP + pl] = ((uint)row[e] << BSHIFT) | (uint)(cc & 511);
            }
        }
    }

    // ---- gemmA part: Y = bf16(X @ W0), no dinv (independent of the build) ----
    int strip = bid * 4 + (t >> 6);
    if (strip < NSTRIP) {
        int lane = t & 63;
        int quad = lane >> 4;
        int m = lane & 15;
        int rowi = strip * 16 + m;

        BF8 a[4];
        #pragma unroll
        for (int kt = 0; kt < 4; kt++) {
            const float* xp = X + (size_t)rowi * DD + kt * 32 + quad * 8;
            float4 v0 = *(const float4*)xp;
            float4 v1 = *(const float4*)(xp + 4);
            a[kt].us[0] = f2bf(v0.x); a[kt].us[1] = f2bf(v0.y);
            a[kt].us[2] = f2bf(v0.z); a[kt].us[3] = f2bf(v0.w);
            a[kt].us[4] = f2bf(v1.x); a[kt].us[5] = f2bf(v1.y);
            a[kt].us[6] = f2bf(v1.z); a[kt].us[7] = f2bf(v1.w);
        }

        #pragma unroll
        for (int nt = 0; nt < 8; nt++) {
            f32x4 acc = {0.f, 0.f, 0.f, 0.f};
            #pragma unroll
            for (int kt = 0; kt < 4; kt++) {
                BF8 b;
                b.u4 = ((const uint4*)Wf)[(nt * 4 + kt) * 64 + lane];
                acc = __builtin_amdgcn_mfma_f32_16x16x32_bf16(a[kt].v, b.v, acc, 0, 0, 0);
            }
            int colg = nt * 16 + m;
            #pragma unroll
            for (int r = 0; r < 4; r++)
                Y[(size_t)(strip * 16 + quad * 4 + r) * DD + colg] = f2bf(acc[r]);
        }
    }
}

// per-bucket finalize: global base from 196-prefix of cnt; row_ptr/dinv/csr
__global__ __launch_bounds__(512)
void kb_fin(const uint* __restrict__ ebuf, const int* __restrict__ cnt,
            int* __restrict__ row_ptr, float* __restrict__ dinv,
            int* __restrict__ csr) {
    __shared__ int deg[512];
    __shared__ int scn[512];
    __shared__ int red[512];
    const int b = blockIdx.x;
    const int t = threadIdx.x;
    red[t] = (t < b) ? cnt[t] : 0;
    __syncthreads();
    #pragma unroll
    for (int off = 256; off > 0; off >>= 1) {
        if (t < off) red[t] += red[t + off];
        __syncthreads();
    }
    const int s = red[0];
    int e = cnt[b]; if (e > CAP) e = CAP;
    const uint* eb = ebuf + (size_t)b * CAP;

    deg[t] = 0;
    __syncthreads();
    for (int p = t; p < e; p += 512)
        atomicAdd(&deg[eb[p] & 511u], 1);
    __syncthreads();
    int d = deg[t];
    scn[t] = d;
    __syncthreads();
    for (int off = 1; off < 512; off <<= 1) {
        int u = (t >= off) ? scn[t - off] : 0;
        __syncthreads();
        scn[t] += u;
        __syncthreads();
    }
    int base = s + scn[t] - d;
    int node = (b << BSHIFT) + t;
    if (node < NN) { row_ptr[node] = base; dinv[node] = rsqrtf((float)(d + 1)); }
    __syncthreads();
    deg[t] = base;
    __syncthreads();
    for (int p = t; p < e; p += 512) {
        uint r = eb[p];
        int pos = atomicAdd(&deg[r & 511u], 1);
        csr[pos] = (int)(r >> BSHIFT);
    }
    if (b == 0 && t == 0) row_ptr[NN] = NE;
}

// -------- GEMM2: Y = bf16(relu(norm(X)) @ W1), UNSCALED (dinv applied in agg2) ----
__global__ __launch_bounds__(256)
void k_gemmB(const uint* __restrict__ Xp, const ushort* __restrict__ Wf,
             const float* __restrict__ psum, const float* __restrict__ psq,
             const float* __restrict__ gw, const float* __restrict__ gb,
             const float* __restrict__ ga,
             ushort* __restrict__ Y) {
    __shared__ float smul[128], sadd[128];
    {
        int f = threadIdx.x;
        if (f < 128) {
            float s = 0.f, q = 0.f;
            #pragma unroll
            for (int sh = 0; sh < NSHARD; sh++) { s += psum[sh * 128 + f]; q += psq[sh * 128 + f]; }
            const float invn = 1.0f / (float)NN;
            float mm = s * invn, ex2 = q * invn, av = ga[f];
            float var = ex2 - mm * mm * (2.f * av - av * av);
            float inv = rsqrtf(var + EPSV);
            smul[f] = gw[f] * inv;
            sadd[f] = gb[f] - gw[f] * inv * av * mm;
        }
    }
    __syncthreads();
    int strip = blockIdx.x * 4 + (threadIdx.x >> 6);
    if (strip >= NSTRIP) return;
    int lane = threadIdx.x & 63;
    int quad = lane >> 4;
    int m = lane & 15;
    int row = strip * 16 + m;

    BF8 a[4];
    #pragma unroll
    for (int kt = 0; kt < 4; kt++) {
        int f = kt * 32 + quad * 8;
        uint4 xu = *(const uint4*)(Xp + (size_t)row * 64 + kt * 16 + quad * 4);
        float4 m0 = *(const float4*)(smul + f);
        float4 m1 = *(const float4*)(smul + f + 4);
        float4 a0 = *(const float4*)(sadd + f);
        float4 a1 = *(const float4*)(sadd + f + 4);
        uint xs[4] = {xu.x, xu.y, xu.z, xu.w};
        float mm[8] = {m0.x, m0.y, m0.z, m0.w, m1.x, m1.y, m1.z, m1.w};
        float aa[8] = {a0.x, a0.y, a0.z, a0.w, a1.x, a1.y, a1.z, a1.w};
        #pragma unroll
        for (int p = 0; p < 4; p++) {
            float lo = bflo(xs[p]), hi = bfhi(xs[p]);
            a[kt].us[2 * p]     = f2bf(fmaxf(0.f, fmaf(lo, mm[2 * p],     aa[2 * p])));
            a[kt].us[2 * p + 1] = f2bf(fmaxf(0.f, fmaf(hi, mm[2 * p + 1], aa[2 * p + 1])));
        }
    }

    #pragma unroll
    for (int nt = 0; nt < 8; nt++) {
        f32x4 acc = {0.f, 0.f, 0.f, 0.f};
        #pragma unroll
        for (int kt = 0; kt < 4; kt++) {
            BF8 b;
            b.u4 = ((const uint4*)Wf)[(nt * 4 + kt) * 64 + lane];
            acc = __builtin_amdgcn_mfma_f32_16x16x32_bf16(a[kt].v, b.v, acc, 0, 0, 0);
        }
        int colg = nt * 16 + m;
        #pragma unroll
        for (int r = 0; r < 4; r++)
            Y[(size_t)(strip * 16 + quad * 4 + r) * DD + colg] = f2bf(acc[r]);
    }
}

// ---------------- aggregation with per-src dinv (R12 body + scalar dinv[s] loads):
// Y[i] = dinv[i]*( sum_e dinv[src]*h[src] + dinv[i]*h[i] ) + bias ----------------
__global__ __launch_bounds__(512)
void k_agg2(const uint* __restrict__ H2,
            const int* __restrict__ row_ptr, const int* __restrict__ csr,
            const float* __restrict__ dinv,
            const float* __restrict__ bias, uint* __restrict__ Y2,
            float* __restrict__ psumG, float* __restrict__ psqG) {
    const int lane = threadIdx.x & 63;
    const int wid  = threadIdx.x >> 6;
    const int i = __builtin_amdgcn_readfirstlane(blockIdx.x * 8 + wid);
    const int p0 = row_ptr[i], p1 = row_ptr[i + 1];
    const float di = dinv[i];
    uint su = H2[(size_t)i * 64 + lane];
    float a0 = bflo(su) * di, a1 = bfhi(su) * di;  // self loop: dinv[i]*h[i]
    float b0 = 0.f, b1 = 0.f, c0 = 0.f, c1 = 0.f, d0 = 0.f, d1 = 0.f;
    int p = p0;
    for (; p + 7 < p1; p += 8) {                   // 8 gathers in flight
        int s0 = csr[p],     s1 = csr[p + 1], s2 = csr[p + 2], s3 = csr[p + 3];
        int s4 = csr[p + 4], s5 = csr[p + 5], s6 = csr[p + 6], s7 = csr[p + 7];
        uint h0 = H2[(size_t)s0 * 64 + lane];
        uint h1 = H2[(size_t)s1 * 64 + lane];
        uint h2 = H2[(size_t)s2 * 64 + lane];
        uint h3 = H2[(size_t)s3 * 64 + lane];
        uint h4 = H2[(size_t)s4 * 64 + lane];
        uint h5 = H2[(size_t)s5 * 64 + lane];
        uint h6 = H2[(size_t)s6 * 64 + lane];
        uint h7 = H2[(size_t)s7 * 64 + lane];
        float v0 = dinv[s0], v1 = dinv[s1], v2 = dinv[s2], v3 = dinv[s3];
        float v4 = dinv[s4], v5 = dinv[s5], v6 = dinv[s6], v7 = dinv[s7];
        a0 = fmaf(bflo(h0), v0, a0); a1 = fmaf(bfhi(h0), v0, a1);
        b0 = fmaf(bflo(h1), v1, b0); b1 = fmaf(bfhi(h1), v1, b1);
        c0 = fmaf(bflo(h2), v2, c0); c1 = fmaf(bfhi(h2), v2, c1);
        d0 = fmaf(bflo(h3), v3, d0); d1 = fmaf(bfhi(h3), v3, d1);
        a0 = fmaf(bflo(h4), v4, a0); a1 = fmaf(bfhi(h4), v4, a1);
        b0 = fmaf(bflo(h5), v5, b0); b1 = fmaf(bfhi(h5), v5, b1);
        c0 = fmaf(bflo(h6), v6, c0); c1 = fmaf(bfhi(h6), v6, c1);
        d0 = fmaf(bflo(h7), v7, d0); d1 = fmaf(bfhi(h7), v7, d1);
    }
    for (; p + 3 < p1; p += 4) {
        int s0 = csr[p], s1 = csr[p + 1], s2 = csr[p + 2], s3 = csr[p + 3];
        uint h0 = H2[(size_t)s0 * 64 + lane];
        uint h1 = H2[(size_t)s1 * 64 + lane];
        uint h2 = H2[(size_t)s2 * 64 + lane];
        uint h3 = H2[(size_t)s3 * 64 + lane];
        float v0 = dinv[s0], v1 = dinv[s1], v2 = dinv[s2], v3 = dinv[s3];
        a0 = fmaf(bflo(h0), v0, a0); a1 = fmaf(bfhi(h0), v0, a1);
        b0 = fmaf(bflo(h1), v1, b0); b1 = fmaf(bfhi(h1), v1, b1);
        c0 = fmaf(bflo(h2), v2, c0); c1 = fmaf(bfhi(h2), v2, c1);
        d0 = fmaf(bflo(h3), v3, d0); d1 = fmaf(bfhi(h3), v3, d1);
    }
    for (; p < p1; p++) {
        int s0 = csr[p];
        uint h0 = H2[(size_t)s0 * 64 + lane];
        float v0 = dinv[s0];
        a0 = fmaf(bflo(h0), v0, a0); a1 = fmaf(bfhi(h0), v0, a1);
    }
    float2 bb = *(const float2*)(bias + 2 * lane);
    float r0 = fmaf((a0 + b0) + (c0 + d0), di, bb.x);
    float r1 = fmaf((a1 + b1) + (c1 + d1), di, bb.y);
    Y2[(size_t)i * 64 + lane] = (uint)f2bf(r0) | ((uint)f2bf(r1) << 16);

    // fused GraphNorm partial stats over the block's 8 nodes
    __shared__ float ls[8][128], lq[8][128];
    ls[wid][2 * lane]     = r0;      ls[wid][2 * lane + 1] = r1;
    lq[wid][2 * lane]     = r0 * r0; lq[wid][2 * lane + 1] = r1 * r1;
    __syncthreads();
    if (threadIdx.x < 128) {
        int f = threadIdx.x;
        float s = ((ls[0][f] + ls[1][f]) + (ls[2][f] + ls[3][f]))
                + ((ls[4][f] + ls[5][f]) + (ls[6][f] + ls[7][f]));
        float q = ((lq[0][f] + lq[1][f]) + (lq[2][f] + lq[3][f]))
                + ((lq[4][f] + lq[5][f]) + (lq[6][f] + lq[7][f]));
        int sh = (blockIdx.x & (NSHARD - 1)) * 128 + f;
        atomicAdd(&psumG[sh], s);
        atomicAdd(&psqG[sh], q);
    }
}

// ------- fused MLP head (MFMA): out = relu(T(norm(X))@W + b0h) @ v1 + b1 ; norm folded ------
__global__ __launch_bounds__(256)
void k_mlp(const uint* __restrict__ Xp, const ushort* __restrict__ Wf,
           const float* __restrict__ psum, const float* __restrict__ psq,
           const float* __restrict__ gw, const float* __restrict__ gb,
           const float* __restrict__ ga,
           const float* __restrict__ b0h, const float* __restrict__ v1,
           const float* __restrict__ b1, float* __restrict__ out) {
    __shared__ float smul[128], sadd[128];
    {
        int f = threadIdx.x;
        if (f < 128) {
            float s = 0.f, q = 0.f;
            #pragma unroll
            for (int sh = 0; sh < NSHARD; sh++) { s += psum[sh * 128 + f]; q += psq[sh * 128 + f]; }
            const float invn = 1.0f / (float)NN;
            float mm = s * invn, ex2 = q * invn, av = ga[f];
            float var = ex2 - mm * mm * (2.f * av - av * av);
            float inv = rsqrtf(var + EPSV);
            smul[f] = gw[f] * inv;
            sadd[f] = gb[f] - gw[f] * inv * av * mm;
        }
    }
    __syncthreads();
    int strip = blockIdx.x * 4 + (threadIdx.x >> 6);
    if (strip >= NSTRIP) return;
    int lane = threadIdx.x & 63;
    int quad = lane >> 4;
    int m = lane & 15;
    int row = strip * 16 + m;

    BF8 a[4];
    #pragma unroll
    for (int kt = 0; kt < 4; kt++) {
        int f = kt * 32 + quad * 8;
        uint4 xu = *(const uint4*)(Xp + (size_t)row * 64 + kt * 16 + quad * 4);
        float4 m0 = *(const float4*)(smul + f);
        float4 m1 = *(const float4*)(smul + f + 4);
        float4 a0 = *(const float4*)(sadd + f);
        float4 a1 = *(const float4*)(sadd + f + 4);
        uint xs[4] = {xu.x, xu.y, xu.z, xu.w};
        float mm[8] = {m0.x, m0.y, m0.z, m0.w, m1.x, m1.y, m1.z, m1.w};
        float aa[8] = {a0.x, a0.y, a0.z, a0.w, a1.x, a1.y, a1.z, a1.w};
        #pragma unroll
        for (int p = 0; p < 4; p++) {
            float lo = bflo(xs[p]), hi = bfhi(xs[p]);
            a[kt].us[2 * p]     = f2bf(fmaxf(0.f, fmaf(lo, mm[2 * p],     aa[2 * p])));
            a[kt].us[2 * p + 1] = f2bf(fmaxf(0.f, fmaf(hi, mm[2 * p + 1], aa[2 * p + 1])));
        }
    }

    float part[4] = {0.f, 0.f, 0.f, 0.f};
    #pragma unroll
    for (int nt = 0; nt < 8; nt++) {
        f32x4 acc = {0.f, 0.f, 0.f, 0.f};
        #pragma unroll
        for (int kt = 0; kt < 4; kt++) {
            BF8 b;
            b.u4 = ((const uint4*)Wf)[(nt * 4 + kt) * 64 + lane];
            acc = __builtin_amdgcn_mfma_f32_16x16x32_bf16(a[kt].v, b.v, acc, 0, 0, 0);
        }
        int colg = nt * 16 + m;
        float bb = b0h[colg];
        float vv = v1[colg];
        #pragma unroll
        for (int r = 0; r < 4; r++)
            part[r] = fmaf(fmaxf(0.f, acc[r] + bb), vv, part[r]);
    }
    #pragma unroll
    for (int r = 0; r < 4; r++) {
        #pragma unroll
        for (int off = 1; off < 16; off <<= 1)
            part[r] += __shfl_xor(part[r], off, 64);
    }
    if (m == 0) {
        float ob = b1[0];
        #pragma unroll
        for (int r = 0; r < 4; r++)
            out[strip * 16 + quad * 4 + r] = part[r] + ob;
    }
}

// ---------------- launch ----------------
static inline char* wsalloc(char*& p, size_t bytes) {
    char* r = p;
    p += (bytes + 255) & ~(size_t)255;
    return r;
}

extern "C" void kernel_launch(void* const* d_in, const int* in_sizes, int n_in,
                              void* d_out, int out_size, void* d_ws, size_t ws_size,
                              hipStream_t stream) {
    const float* x     = (const float*)d_in[0];
    const int*   ei    = (const int*)d_in[1];
    const int*   erow  = ei;
    const int*   ecol  = ei + NE;
    const float* W0    = (const float*)d_in[2];
    const float* b0    = (const float*)d_in[3];
    const float* W1    = (const float*)d_in[4];
    const float* b1    = (const float*)d_in[5];
    const float* gn0w  = (const float*)d_in[6];
    const float* gn0b  = (const float*)d_in[7];
    const float* gn0a  = (const float*)d_in[8];
    const float* gn1w  = (const float*)d_in[9];
    const float* gn1b  = (const float*)d_in[10];
    const float* gn1a  = (const float*)d_in[11];
    const float* lin0w = (const float*)d_in[12];
    const float* lin0b = (const float*)d_in[13];
    const float* lin1w = (const float*)d_in[14];
    const float* lin1b = (const float*)d_in[15];
    float* out = (float*)d_out;

    char* p = (char*)d_ws;
    ushort* bufA   = (ushort*)wsalloc(p, (size_t)NN * DD * 2);   // bf16 h (UNSCALED)
    ushort* bufB   = (ushort*)wsalloc(p, (size_t)NN * DD * 2);   // bf16 agg out
    int*    csr    = (int*)   wsalloc(p, (size_t)NE * 4);        // src only
    uint*   ebuf   = (uint*)  wsalloc(p, (size_t)NBUCK * CAP * 4); // padded buckets
    int*    cnt    = (int*)   wsalloc(p, 256 * 4);
    int*    row_ptr= (int*)   wsalloc(p, (size_t)(NN + 1) * 4);
    float*  dinv   = (float*) wsalloc(p, (size_t)NN * 4);
    float*  statsG = (float*) wsalloc(p, STATS_F * 4);
    ushort* Wf     = (ushort*)wsalloc(p, 3 * 2048 * 8 * 2);      // 3 prepped weights

    // 1) weight prep + zero scratch (cnt, statsG)
    k_prepw3<<<24, 256, 0, stream>>>(W0, W1, lin0w, Wf, cnt, statsG);
    ushort* Wf0 = Wf;
    ushort* Wf1 = Wf + 2048 * 8;
    ushort* Wf2 = Wf + 2 * 2048 * 8;

    const int GB = (NSTRIP + 3) / 4;   // 1563 blocks for gemm-shaped kernels

    // 2) FUSED hist+place (blocks<782) + GEMM1 unscaled (all blocks)
    kb_histplaceA<<<GB, 256, 0, stream>>>(erow, ecol, cnt, ebuf, x, Wf0, bufA);

    // 3) per-bucket finalize (row_ptr / dinv / csr)
    kb_fin<<<NBUCK, 512, 0, stream>>>(ebuf, cnt, row_ptr, dinv, csr);

    float* ps0 = statsG;
    float* pq0 = statsG + NSHARD * 128;
    float* ps1 = statsG + 2 * NSHARD * 128;
    float* pq1 = statsG + 3 * NSHARD * 128;

    // 4) aggregation stage 1 (applies dinv[src] per neighbor)
    k_agg2<<<NN / 8, 512, 0, stream>>>((const uint*)bufA, row_ptr, csr, dinv, b0,
                                       (uint*)bufB, ps0, pq0);

    // 5) GEMM2 (norm folded; unscaled output)
    k_gemmB<<<GB, 256, 0, stream>>>((const uint*)bufB, Wf1, ps0, pq0,
                                    gn0w, gn0b, gn0a, bufA);

    // 6) aggregation stage 2
    k_agg2<<<NN / 8, 512, 0, stream>>>((const uint*)bufA, row_ptr, csr, dinv, b1,
                                       (uint*)bufB, ps1, pq1);

    // 7) fused MLP head (norm folded)
    k_mlp<<<GB, 256, 0, stream>>>((const uint*)bufB, Wf2, ps1, pq1,
                                  gn1w, gn1b, gn1a,
                                  lin0b, lin1w, lin1b, out);

    (void)in_sizes; (void)n_in; (void)out_size; (void)ws_size;
}

// Round 14
// 338.472 us; speedup vs baseline: 1.0079x; 1.0079x over previous
//
#include <hip/hip_runtime.h>

// ---------------- problem constants ----------------
#define NN 100000      // nodes
#define NE 1600000     // edges (without self loops)
#define DD 128         // feature dim
#define EPSV 1e-5f

#define NSTRIP 6250            // NN/16 row-strips for MFMA gemms

// bucket sort: 196 buckets of 512 nodes; 782 histplace blocks of 2048 edges
#define BSHIFT 9
#define NBUCK 196
#define EPB 2048
#define NHB 782
#define CAP 12288              // fixed bucket capacity (mean 8163, sd~90: 45 sigma)

#define NSHARD 32              // stats atomic shards
#define STATS_F (4 * NSHARD * 128)   // 2 stages x (sum|sq)[32][128]

typedef __attribute__((ext_vector_type(8))) __bf16 bf16x8;
typedef __attribute__((ext_vector_type(4))) float f32x4;

union BF8 {                // bit-level construction of MFMA bf16 fragments
    ushort  us[8];
    uint    ui[4];
    uint4   u4;
    bf16x8  v;
};

__device__ __forceinline__ ushort f2bf(float f) {   // RNE fp32 -> bf16 bits
    uint u = __float_as_uint(f);
    return (ushort)((u + 0x7fffu + ((u >> 16) & 1u)) >> 16);
}
__device__ __forceinline__ float bflo(uint u) { return __uint_as_float(u << 16); }
__device__ __forceinline__ float bfhi(uint u) { return __uint_as_float(u & 0xffff0000u); }

// ------ weight prep (runs FIRST): 3x W[128x128] fp32 -> B-frag bf16 + zero scratch ------
__global__ void k_prepw3(const float* __restrict__ WA, const float* __restrict__ WB,
                         const float* __restrict__ WC, ushort* __restrict__ Wf,
                         int* __restrict__ cnt, float* __restrict__ statsG) {
    int gid = blockIdx.x * 256 + threadIdx.x;        // 0..6143
    if (gid < 256) cnt[gid] = 0;
    for (int i = gid; i < STATS_F; i += 24 * 256) statsG[i] = 0.f;

    int which = blockIdx.x >> 3;
    const float* W = (which == 0) ? WA : ((which == 1) ? WB : WC);
    int t = (blockIdx.x & 7) * 256 + threadIdx.x;    // 0..2047
    int lane = t & 63;
    int kt = (t >> 6) & 3;
    int nt = t >> 8;
    int quad = lane >> 4;
    int n = nt * 16 + (lane & 15);
    BF8 f;
    #pragma unroll
    for (int j = 0; j < 8; j++)
        f.us[j] = f2bf(W[(kt * 32 + quad * 8 + j) * DD + n]);
    ((uint4*)(Wf + (size_t)which * 2048 * 8))[t] = f.u4;
}

// ---- FUSED hist+place: LDS hist -> one global atomic per bucket (reservation) ->
//      place into fixed-capacity bucket slot. No global scan, no blk_off. ----
__global__ __launch_bounds__(256)
void kb_histplace(const int* __restrict__ row, const int* __restrict__ col,
                  int* __restrict__ cnt, uint* __restrict__ ebuf) {
    __shared__ int h[256];
    __shared__ int curl[256];      // per-bucket local cursor (offset within bucket)
    int t = threadIdx.x;
    h[t] = 0;
    __syncthreads();
    int e0 = blockIdx.x * EPB;
    #pragma unroll
    for (int j = 0; j < 8; j++) {
        int e = e0 + t + j * 256;
        if (e < NE) atomicAdd(&h[col[e] >> BSHIFT], 1);
    }
    __syncthreads();
    int c = h[t];
    curl[t] = c ? atomicAdd(&cnt[t], c) : 0;   // block's reservation in bucket t
    __syncthreads();
    #pragma unroll
    for (int j = 0; j < 8; j++) {
        int e = e0 + t + j * 256;
        if (e < NE) {
            int cc = col[e];
            int b = cc >> BSHIFT;
            int pl = atomicAdd(&curl[b], 1);
            if (pl < CAP)                      // 45-sigma guard; no drops in practice
                ebuf[(size_t)b * CAP + pl] = ((uint)row[e] << BSHIFT) | (uint)(cc & 511);
        }
    }
}

// per-bucket finalize: global base from 196-prefix of cnt; row_ptr/dinv/csr as R8
__global__ __launch_bounds__(512)
void kb_fin(const uint* __restrict__ ebuf, const int* __restrict__ cnt,
            int* __restrict__ row_ptr, float* __restrict__ dinv,
            int* __restrict__ csr) {
    __shared__ int deg[512];
    __shared__ int scn[512];
    __shared__ int red[512];
    const int b = blockIdx.x;
    const int t = threadIdx.x;
    // s = sum cnt[0..b) (b<=195 so at most one element per thread)
    red[t] = (t < b) ? cnt[t] : 0;
    __syncthreads();
    #pragma unroll
    for (int off = 256; off > 0; off >>= 1) {
        if (t < off) red[t] += red[t + off];
        __syncthreads();
    }
    const int s = red[0];
    int e = cnt[b]; if (e > CAP) e = CAP;
    const uint* eb = ebuf + (size_t)b * CAP;

    deg[t] = 0;
    __syncthreads();
    for (int p = t; p < e; p += 512)
        atomicAdd(&deg[eb[p] & 511u], 1);
    __syncthreads();
    int d = deg[t];
    scn[t] = d;
    __syncthreads();
    for (int off = 1; off < 512; off <<= 1) {
        int u = (t >= off) ? scn[t - off] : 0;
        __syncthreads();
        scn[t] += u;
        __syncthreads();
    }
    int base = s + scn[t] - d;                 // global CSR offset of node n0+t
    int node = (b << BSHIFT) + t;
    if (node < NN) { row_ptr[node] = base; dinv[node] = rsqrtf((float)(d + 1)); }
    __syncthreads();                           // before reusing deg[] as cursors
    deg[t] = base;
    __syncthreads();
    for (int p = t; p < e; p += 512) {
        uint r = eb[p];
        int pos = atomicAdd(&deg[r & 511u], 1);
        csr[pos] = (int)(r >> BSHIFT);         // 4B record: src only
    }
    if (b == 0 && t == 0) row_ptr[NN] = NE;
}

// ---------------- GEMM1: G_bf16[N,128] = (bf16(X_f32) @ Wf) * dinv[row] ----------------
__global__ __launch_bounds__(256)
void k_gemmA(const float* __restrict__ X, const ushort* __restrict__ Wf,
             const float* __restrict__ dinv, ushort* __restrict__ Y) {
    int strip = blockIdx.x * 4 + (threadIdx.x >> 6);
    if (strip >= NSTRIP) return;
    int lane = threadIdx.x & 63;
    int quad = lane >> 4;
    int m = lane & 15;
    int row = strip * 16 + m;

    BF8 a[4];
    #pragma unroll
    for (int kt = 0; kt < 4; kt++) {
        const float* xp = X + (size_t)row * DD + kt * 32 + quad * 8;
        float4 v0 = *(const float4*)xp;
        float4 v1 = *(const float4*)(xp + 4);
        a[kt].us[0] = f2bf(v0.x); a[kt].us[1] = f2bf(v0.y);
        a[kt].us[2] = f2bf(v0.z); a[kt].us[3] = f2bf(v0.w);
        a[kt].us[4] = f2bf(v1.x); a[kt].us[5] = f2bf(v1.y);
        a[kt].us[6] = f2bf(v1.z); a[kt].us[7] = f2bf(v1.w);
    }

    float4 dv = *(const float4*)(dinv + strip * 16 + quad * 4);
    float dvr[4] = {dv.x, dv.y, dv.z, dv.w};

    #pragma unroll
    for (int nt = 0; nt < 8; nt++) {
        f32x4 acc = {0.f, 0.f, 0.f, 0.f};
        #pragma unroll
        for (int kt = 0; kt < 4; kt++) {
            BF8 b;
            b.u4 = ((const uint4*)Wf)[(nt * 4 + kt) * 64 + lane];
            acc = __builtin_amdgcn_mfma_f32_16x16x32_bf16(a[kt].v, b.v, acc, 0, 0, 0);
        }
        int colg = nt * 16 + m;
        #pragma unroll
        for (int r = 0; r < 4; r++)
            Y[(size_t)(strip * 16 + quad * 4 + r) * DD + colg] = f2bf(acc[r] * dvr[r]);
    }
}

// -------- GEMM2: G = (bf16(relu(norm(X_bf16))) @ Wf) * dinv ; norm params from partials ----
__global__ __launch_bounds__(256)
void k_gemmB(const uint* __restrict__ Xp, const ushort* __restrict__ Wf,
             const float* __restrict__ psum, const float* __restrict__ psq,
             const float* __restrict__ gw, const float* __restrict__ gb,
             const float* __restrict__ ga,
             const float* __restrict__ dinv, ushort* __restrict__ Y) {
    __shared__ float smul[128], sadd[128];
    {
        int f = threadIdx.x;
        if (f < 128) {
            float s = 0.f, q = 0.f;
            #pragma unroll
            for (int sh = 0; sh < NSHARD; sh++) { s += psum[sh * 128 + f]; q += psq[sh * 128 + f]; }
            const float invn = 1.0f / (float)NN;
            float mm = s * invn, ex2 = q * invn, av = ga[f];
            float var = ex2 - mm * mm * (2.f * av - av * av);
            float inv = rsqrtf(var + EPSV);
            smul[f] = gw[f] * inv;
            sadd[f] = gb[f] - gw[f] * inv * av * mm;
        }
    }
    __syncthreads();
    int strip = blockIdx.x * 4 + (threadIdx.x >> 6);
    if (strip >= NSTRIP) return;
    int lane = threadIdx.x & 63;
    int quad = lane >> 4;
    int m = lane & 15;
    int row = strip * 16 + m;

    BF8 a[4];
    #pragma unroll
    for (int kt = 0; kt < 4; kt++) {
        int f = kt * 32 + quad * 8;
        uint4 xu = *(const uint4*)(Xp + (size_t)row * 64 + kt * 16 + quad * 4);
        float4 m0 = *(const float4*)(smul + f);
        float4 m1 = *(const float4*)(smul + f + 4);
        float4 a0 = *(const float4*)(sadd + f);
        float4 a1 = *(const float4*)(sadd + f + 4);
        uint xs[4] = {xu.x, xu.y, xu.z, xu.w};
        float mm[8] = {m0.x, m0.y, m0.z, m0.w, m1.x, m1.y, m1.z, m1.w};
        float aa[8] = {a0.x, a0.y, a0.z, a0.w, a1.x, a1.y, a1.z, a1.w};
        #pragma unroll
        for (int p = 0; p < 4; p++) {
            float lo = bflo(xs[p]), hi = bfhi(xs[p]);
            a[kt].us[2 * p]     = f2bf(fmaxf(0.f, fmaf(lo, mm[2 * p],     aa[2 * p])));
            a[kt].us[2 * p + 1] = f2bf(fmaxf(0.f, fmaf(hi, mm[2 * p + 1], aa[2 * p + 1])));
        }
    }

    float4 dv = *(const float4*)(dinv + strip * 16 + quad * 4);
    float dvr[4] = {dv.x, dv.y, dv.z, dv.w};

    #pragma unroll
    for (int nt = 0; nt < 8; nt++) {
        f32x4 acc = {0.f, 0.f, 0.f, 0.f};
        #pragma unroll
        for (int kt = 0; kt < 4; kt++) {
            BF8 b;
            b.u4 = ((const uint4*)Wf)[(nt * 4 + kt) * 64 + lane];
            acc = __builtin_amdgcn_mfma_f32_16x16x32_bf16(a[kt].v, b.v, acc, 0, 0, 0);
        }
        int colg = nt * 16 + m;
        #pragma unroll
        for (int r = 0; r < 4; r++)
            Y[(size_t)(strip * 16 + quad * 4 + r) * DD + colg] = f2bf(acc[r] * dvr[r]);
    }
}

// ---------------- aggregation (R8-proven): 8 waves = 8 nodes/block ----------------
__global__ __launch_bounds__(512)
void k_agg2(const uint* __restrict__ H2,
            const int* __restrict__ row_ptr, const int* __restrict__ csr,
            const float* __restrict__ dinv,
            const float* __restrict__ bias, uint* __restrict__ Y2,
            float* __restrict__ psumG, float* __restrict__ psqG) {
    const int lane = threadIdx.x & 63;
    const int wid  = threadIdx.x >> 6;
    const int i = __builtin_amdgcn_readfirstlane(blockIdx.x * 8 + wid);
    const int p0 = row_ptr[i], p1 = row_ptr[i + 1];
    const float di = dinv[i];
    uint su = H2[(size_t)i * 64 + lane];
    float a0 = bflo(su), a1 = bfhi(su);            // self loop term g[i]
    float b0 = 0.f, b1 = 0.f, c0 = 0.f, c1 = 0.f, d0 = 0.f, d1 = 0.f;
    int p = p0;
    for (; p + 7 < p1; p += 8) {                   // 8 loads in flight
        int s0 = csr[p],     s1 = csr[p + 1], s2 = csr[p + 2], s3 = csr[p + 3];
        int s4 = csr[p + 4], s5 = csr[p + 5], s6 = csr[p + 6], s7 = csr[p + 7];
        uint h0 = H2[(size_t)s0 * 64 + lane];
        uint h1 = H2[(size_t)s1 * 64 + lane];
        uint h2 = H2[(size_t)s2 * 64 + lane];
        uint h3 = H2[(size_t)s3 * 64 + lane];
        uint h4 = H2[(size_t)s4 * 64 + lane];
        uint h5 = H2[(size_t)s5 * 64 + lane];
        uint h6 = H2[(size_t)s6 * 64 + lane];
        uint h7 = H2[(size_t)s7 * 64 + lane];
        a0 += bflo(h0); a1 += bfhi(h0);
        b0 += bflo(h1); b1 += bfhi(h1);
        c0 += bflo(h2); c1 += bfhi(h2);
        d0 += bflo(h3); d1 += bfhi(h3);
        a0 += bflo(h4); a1 += bfhi(h4);
        b0 += bflo(h5); b1 += bfhi(h5);
        c0 += bflo(h6); c1 += bfhi(h6);
        d0 += bflo(h7); d1 += bfhi(h7);
    }
    for (; p + 3 < p1; p += 4) {
        int s0 = csr[p], s1 = csr[p + 1], s2 = csr[p + 2], s3 = csr[p + 3];
        uint h0 = H2[(size_t)s0 * 64 + lane];
        uint h1 = H2[(size_t)s1 * 64 + lane];
        uint h2 = H2[(size_t)s2 * 64 + lane];
        uint h3 = H2[(size_t)s3 * 64 + lane];
        a0 += bflo(h0); a1 += bfhi(h0);
        b0 += bflo(h1); b1 += bfhi(h1);
        c0 += bflo(h2); c1 += bfhi(h2);
        d0 += bflo(h3); d1 += bfhi(h3);
    }
    for (; p < p1; p++) {
        uint h0 = H2[(size_t)csr[p] * 64 + lane];
        a0 += bflo(h0); a1 += bfhi(h0);
    }
    float2 bb = *(const float2*)(bias + 2 * lane);
    float r0 = fmaf((a0 + b0) + (c0 + d0), di, bb.x);
    float r1 = fmaf((a1 + b1) + (c1 + d1), di, bb.y);
    Y2[(size_t)i * 64 + lane] = (uint)f2bf(r0) | ((uint)f2bf(r1) << 16);

    // fused GraphNorm partial stats over the block's 8 nodes
    __shared__ float ls[8][128], lq[8][128];
    ls[wid][2 * lane]     = r0;      ls[wid][2 * lane + 1] = r1;
    lq[wid][2 * lane]     = r0 * r0; lq[wid][2 * lane + 1] = r1 * r1;
    __syncthreads();
    if (threadIdx.x < 128) {
        int f = threadIdx.x;
        float s = ((ls[0][f] + ls[1][f]) + (ls[2][f] + ls[3][f]))
                + ((ls[4][f] + ls[5][f]) + (ls[6][f] + ls[7][f]));
        float q = ((lq[0][f] + lq[1][f]) + (lq[2][f] + lq[3][f]))
                + ((lq[4][f] + lq[5][f]) + (lq[6][f] + lq[7][f]));
        int sh = (blockIdx.x & (NSHARD - 1)) * 128 + f;
        atomicAdd(&psumG[sh], s);
        atomicAdd(&psqG[sh], q);
    }
}

// ------- fused MLP head (MFMA): out = relu(T(norm(X))@W + b0h) @ v1 + b1 ; norm folded ------
__global__ __launch_bounds__(256)
void k_mlp(const uint* __restrict__ Xp, const ushort* __restrict__ Wf,
           const float* __restrict__ psum, const float* __restrict__ psq,
           const float* __restrict__ gw, const float* __restrict__ gb,
           const float* __restrict__ ga,
           const float* __restrict__ b0h, const float* __restrict__ v1,
           const float* __restrict__ b1, float* __restrict__ out) {
    __shared__ float smul[128], sadd[128];
    {
        int f = threadIdx.x;
        if (f < 128) {
            float s = 0.f, q = 0.f;
            #pragma unroll
            for (int sh = 0; sh < NSHARD; sh++) { s += psum[sh * 128 + f]; q += psq[sh * 128 + f]; }
            const float invn = 1.0f / (float)NN;
            float mm = s * invn, ex2 = q * invn, av = ga[f];
            float var = ex2 - mm * mm * (2.f * av - av * av);
            float inv = rsqrtf(var + EPSV);
            smul[f] = gw[f] * inv;
            sadd[f] = gb[f] - gw[f] * inv * av * mm;
        }
    }
    __syncthreads();
    int strip = blockIdx.x * 4 + (threadIdx.x >> 6);
    if (strip >= NSTRIP) return;
    int lane = threadIdx.x & 63;
    int quad = lane >> 4;
    int m = lane & 15;
    int row = strip * 16 + m;

    BF8 a[4];
    #pragma unroll
    for (int kt = 0; kt < 4; kt++) {
        int f = kt * 32 + quad * 8;
        uint4 xu = *(const uint4*)(Xp + (size_t)row * 64 + kt * 16 + quad * 4);
        float4 m0 = *(const float4*)(smul + f);
        float4 m1 = *(const float4*)(smul + f + 4);
        float4 a0 = *(const float4*)(sadd + f);
        float4 a1 = *(const float4*)(sadd + f + 4);
        uint xs[4] = {xu.x, xu.y, xu.z, xu.w};
        float mm[8] = {m0.x, m0.y, m0.z, m0.w, m1.x, m1.y, m1.z, m1.w};
        float aa[8] = {a0.x, a0.y, a0.z, a0.w, a1.x, a1.y, a1.z, a1.w};
        #pragma unroll
        for (int p = 0; p < 4; p++) {
            float lo = bflo(xs[p]), hi = bfhi(xs[p]);
            a[kt].us[2 * p]     = f2bf(fmaxf(0.f, fmaf(lo, mm[2 * p],     aa[2 * p])));
            a[kt].us[2 * p + 1] = f2bf(fmaxf(0.f, fmaf(hi, mm[2 * p + 1], aa[2 * p + 1])));
        }
    }

    float part[4] = {0.f, 0.f, 0.f, 0.f};
    #pragma unroll
    for (int nt = 0; nt < 8; nt++) {
        f32x4 acc = {0.f, 0.f, 0.f, 0.f};
        #pragma unroll
        for (int kt = 0; kt < 4; kt++) {
            BF8 b;
            b.u4 = ((const uint4*)Wf)[(nt * 4 + kt) * 64 + lane];
            acc = __builtin_amdgcn_mfma_f32_16x16x32_bf16(a[kt].v, b.v, acc, 0, 0, 0);
        }
        int colg = nt * 16 + m;
        float bb = b0h[colg];
        float vv = v1[colg];
        #pragma unroll
        for (int r = 0; r < 4; r++)
            part[r] = fmaf(fmaxf(0.f, acc[r] + bb), vv, part[r]);
    }
    #pragma unroll
    for (int r = 0; r < 4; r++) {
        #pragma unroll
        for (int off = 1; off < 16; off <<= 1)
            part[r] += __shfl_xor(part[r], off, 64);
    }
    if (m == 0) {
        float ob = b1[0];
        #pragma unroll
        for (int r = 0; r < 4; r++)
            out[strip * 16 + quad * 4 + r] = part[r] + ob;
    }
}

// ---------------- launch ----------------
static inline char* wsalloc(char*& p, size_t bytes) {
    char* r = p;
    p += (bytes + 255) & ~(size_t)255;
    return r;
}

extern "C" void kernel_launch(void* const* d_in, const int* in_sizes, int n_in,
                              void* d_out, int out_size, void* d_ws, size_t ws_size,
                              hipStream_t stream) {
    const float* x     = (const float*)d_in[0];
    const int*   ei    = (const int*)d_in[1];
    const int*   erow  = ei;
    const int*   ecol  = ei + NE;
    const float* W0    = (const float*)d_in[2];
    const float* b0    = (const float*)d_in[3];
    const float* W1    = (const float*)d_in[4];
    const float* b1    = (const float*)d_in[5];
    const float* gn0w  = (const float*)d_in[6];
    const float* gn0b  = (const float*)d_in[7];
    const float* gn0a  = (const float*)d_in[8];
    const float* gn1w  = (const float*)d_in[9];
    const float* gn1b  = (const float*)d_in[10];
    const float* gn1a  = (const float*)d_in[11];
    const float* lin0w = (const float*)d_in[12];
    const float* lin0b = (const float*)d_in[13];
    const float* lin1w = (const float*)d_in[14];
    const float* lin1b = (const float*)d_in[15];
    float* out = (float*)d_out;

    char* p = (char*)d_ws;
    ushort* bufA   = (ushort*)wsalloc(p, (size_t)NN * DD * 2);   // bf16 g = h*dinv
    ushort* bufB   = (ushort*)wsalloc(p, (size_t)NN * DD * 2);   // bf16 agg out
    int*    csr    = (int*)   wsalloc(p, (size_t)NE * 4);        // src only
    uint*   ebuf   = (uint*)  wsalloc(p, (size_t)NBUCK * CAP * 4); // padded buckets
    int*    cnt    = (int*)   wsalloc(p, 256 * 4);
    int*    row_ptr= (int*)   wsalloc(p, (size_t)(NN + 1) * 4);
    float*  dinv   = (float*) wsalloc(p, (size_t)NN * 4);
    float*  statsG = (float*) wsalloc(p, STATS_F * 4);
    ushort* Wf     = (ushort*)wsalloc(p, 3 * 2048 * 8 * 2);      // 3 prepped weights

    // 1) weight prep + zero scratch (cnt, statsG)
    k_prepw3<<<24, 256, 0, stream>>>(W0, W1, lin0w, Wf, cnt, statsG);
    ushort* Wf0 = Wf;
    ushort* Wf1 = Wf + 2048 * 8;
    ushort* Wf2 = Wf + 2 * 2048 * 8;

    // 2) FUSED hist+place into fixed-capacity buckets
    kb_histplace<<<NHB, 256, 0, stream>>>(erow, ecol, cnt, ebuf);

    // 3) per-bucket finalize (row_ptr / dinv / csr; global base from cnt-prefix)
    kb_fin<<<NBUCK, 512, 0, stream>>>(ebuf, cnt, row_ptr, dinv, csr);

    const int GB = (NSTRIP + 3) / 4;   // 1563 blocks for gemm-shaped kernels

    float* ps0 = statsG;
    float* pq0 = statsG + NSHARD * 128;
    float* ps1 = statsG + 2 * NSHARD * 128;
    float* pq1 = statsG + 3 * NSHARD * 128;

    // 4) GEMM1
    k_gemmA<<<GB, 256, 0, stream>>>(x, Wf0, dinv, bufA);

    // 5) aggregation stage 1
    k_agg2<<<NN / 8, 512, 0, stream>>>((const uint*)bufA, row_ptr, csr, dinv, b0,
                                       (uint*)bufB, ps0, pq0);

    // 6) GEMM2 (GraphNorm params folded into prologue)
    k_gemmB<<<GB, 256, 0, stream>>>((const uint*)bufB, Wf1, ps0, pq0,
                                    gn0w, gn0b, gn0a, dinv, bufA);

    // 7) aggregation stage 2
    k_agg2<<<NN / 8, 512, 0, stream>>>((const uint*)bufA, row_ptr, csr, dinv, b1,
                                       (uint*)bufB, ps1, pq1);

    // 8) fused MLP head (GraphNorm params folded into prologue)
    k_mlp<<<GB, 256, 0, stream>>>((const uint*)bufB, Wf2, ps1, pq1,
                                  gn1w, gn1b, gn1a,
                                  lin0b, lin1w, lin1b, out);

    (void)in_sizes; (void)n_in; (void)out_size; (void)ws_size;
}